// Round 8
// baseline (270.431 us; speedup 1.0000x reference)
//
#include <hip/hip_runtime.h>
#include <math.h>

typedef __bf16 bf16x8 __attribute__((ext_vector_type(8)));
typedef __bf16 bf16x4 __attribute__((ext_vector_type(4)));
typedef float  f32x4  __attribute__((ext_vector_type(4)));

#define QL    32
#define DL    256
#define DIM   256
#define NK    21
#define KSOFT 20
#define STR   264                 // LDS row stride in bf16: 528 B, 16-B aligned
#define L2E   1.4426950408889634f

#if __has_builtin(__builtin_amdgcn_exp2f)
#define EXP2F(x) __builtin_amdgcn_exp2f(x)
#else
#define EXP2F(x) exp2f(x)
#endif

// ---------- Phase 1: stream-normalize emb -> bf16 table in ws (4 rows/wave) --
__global__ __launch_bounds__(256)
void knrm_prep(const float* __restrict__ emb, __bf16* __restrict__ tab, int V)
{
    const int wave = threadIdx.x >> 6;
    const int lane = threadIdx.x & 63;
    const int row0 = (blockIdx.x * 4 + wave) * 4;
    if (row0 >= V) return;                     // V % 16 == 0 -> all 4 valid

    float4 v[4];
    #pragma unroll
    for (int i = 0; i < 4; ++i)
        v[i] = reinterpret_cast<const float4*>(emb + (size_t)(row0 + i) * DIM)[lane];
    float s[4];
    #pragma unroll
    for (int i = 0; i < 4; ++i)
        s[i] = v[i].x*v[i].x + v[i].y*v[i].y + v[i].z*v[i].z + v[i].w*v[i].w;
    #pragma unroll
    for (int m = 32; m; m >>= 1) {
        #pragma unroll
        for (int i = 0; i < 4; ++i) s[i] += __shfl_xor(s[i], m);
    }
    #pragma unroll
    for (int i = 0; i < 4; ++i) {
        float inv = rsqrtf(fmaxf(s[i], 1e-16f));   // ||row|| ~16, eps never binds
        bf16x4 o;
        o[0] = (__bf16)(v[i].x * inv); o[1] = (__bf16)(v[i].y * inv);
        o[2] = (__bf16)(v[i].z * inv); o[3] = (__bf16)(v[i].w * inv);
        *reinterpret_cast<bf16x4*>(tab + (size_t)(row0 + i) * DIM + lane * 4) = o;
    }
}

// ---------- Phase 2: doc-split main. grid (B, pair, dh); 4 tiles per block ---
// A=doc, B=query (C col == q-row, acc[21]/lane). Partial Sqk -> disjoint
// global slots; no atomics, no zero-init.
__global__ __launch_bounds__(256, 4)
void knrm_main6(const int* __restrict__ q1t, const int* __restrict__ d1t,
                const int* __restrict__ q2t, const int* __restrict__ d2t,
                const __bf16* __restrict__ tab,
                float* __restrict__ gSqk, int B)
{
    const int b    = blockIdx.x;
    const int pair = blockIdx.y;
    const int dh   = blockIdx.z;    // doc half: rows dh*128 .. dh*128+127
    const int tid  = threadIdx.x;
    const int wave = tid >> 6;
    const int lane = tid & 63;
    const int qt   = wave >> 1;     // q half (B operand)
    const int dt   = wave & 1;      // doc half within tile (A operand)
    const int g    = lane >> 4;     // k-chunk group == C row group (doc rows)
    const int cl   = lane & 15;     // A row / B row / C col
    const int hl   = lane & 31;
    const int hw   = lane >> 5;

    const int* qtok = pair ? q2t : q1t;
    const int* dtok = pair ? d2t : d1t;

    __shared__ __align__(16) __bf16 qbuf[QL * STR];
    __shared__ __align__(16) __bf16 dbuf[32 * STR];
    __shared__ float Sqk[QL * NK];
    __shared__ int   dtok_s[128];
    __shared__ int   qtok_s[QL];

    if (tid < QL)  qtok_s[tid] = qtok[b * QL + tid];
    if (tid < 128) dtok_s[tid] = dtok[b * DL + dh * 128 + tid];
    for (int e = tid; e < QL * NK; e += 256) Sqk[e] = 0.0f;
    __syncthreads();

    // ---- stage 8 query rows per wave (pre-normalized bf16; 2 rows per load)
    {
        bf16x8 qv[4];
        #pragma unroll
        for (int i = 0; i < 4; ++i) {
            int r = wave * 8 + i * 2 + hw;
            qv[i] = *reinterpret_cast<const bf16x8*>(
                tab + (size_t)qtok_s[r] * DIM + hl * 8);
        }
        #pragma unroll
        for (int i = 0; i < 4; ++i) {
            int r = wave * 8 + i * 2 + hw;
            *reinterpret_cast<bf16x8*>(&qbuf[r * STR + hl * 8]) = qv[i];
        }
    }

    // ---- prefetch doc tile 0
    bf16x8 dreg[4];
    #pragma unroll
    for (int i = 0; i < 4; ++i) {
        int r = wave * 8 + i * 2 + hw;
        dreg[i] = *reinterpret_cast<const bf16x8*>(
            tab + (size_t)dtok_s[r] * DIM + hl * 8);
    }

    const int myq  = qt * 16 + cl;      // fixed q-row for this lane
    const int qtk1 = qtok_s[myq];

    float acc[NK];
    #pragma unroll
    for (int k = 0; k < NK; ++k) acc[k] = 0.0f;

    for (int tile = 0; tile < 4; ++tile) {
        __syncthreads();   // prev tile's dbuf reads done; qbuf ready @tile=0

        #pragma unroll
        for (int i = 0; i < 4; ++i) {
            int r = wave * 8 + i * 2 + hw;
            *reinterpret_cast<bf16x8*>(&dbuf[r * STR + hl * 8]) = dreg[i];
        }
        if (tile < 3) {
            #pragma unroll
            for (int i = 0; i < 4; ++i) {
                int r = wave * 8 + i * 2 + hw;
                dreg[i] = *reinterpret_cast<const bf16x8*>(
                    tab + (size_t)dtok_s[(tile + 1) * 32 + r] * DIM + hl * 8);
            }
        }
        __syncthreads();   // dbuf(tile) visible

        // ---- 16x16x32 MFMA over K=256, A = doc rows, B = query rows
        f32x4 cf = {0.0f, 0.0f, 0.0f, 0.0f};
        #pragma unroll
        for (int ks = 0; ks < 8; ++ks) {
            bf16x8 dfr = *reinterpret_cast<const bf16x8*>(&dbuf[(dt*16 + cl)*STR + ks*32 + g*8]);
            bf16x8 qfr = *reinterpret_cast<const bf16x8*>(&qbuf[(qt*16 + cl)*STR + ks*32 + g*8]);
            cf = __builtin_amdgcn_mfma_f32_16x16x32_bf16(dfr, qfr, cf, 0, 0, 0);
        }

        // ---- eval: cf[i] = mm[doc = tile*32+dt*16+g*4+i][q = myq]
        #pragma unroll
        for (int i = 0; i < 4; ++i) {
            float mm  = cf[i];
            float mm2 = mm * mm;
            #pragma unroll
            for (int k = 0; k < KSOFT; ++k) {
                float mu = -0.95f + 0.1f * (float)k;          // compile-time
                float a1 = 100.0f * L2E * mu;
                float a0 = -50.0f * L2E * mu * mu;
                float arg = fmaf(a1, mm, fmaf(-50.0f * L2E, mm2, a0));
                acc[k] += EXP2F(arg);
            }
            // exact kernel (sigma=0.001) == 1[token match]
            int drow = tile*32 + dt*16 + g*4 + i;
            acc[KSOFT] += (dtok_s[drow] == qtk1) ? 1.0f : 0.0f;
        }
    }

    // ---- merge 8 lanes per q-row into LDS Sqk, then plain-store to ws slot
    #pragma unroll
    for (int k = 0; k < NK; ++k)
        atomicAdd(&Sqk[myq * NK + k], acc[k]);
    __syncthreads();

    float* gp = gSqk + ((((size_t)pair * B + b) * 2 + dh) * (QL * NK));
    for (int e = tid; e < QL * NK; e += 256) gp[e] = Sqk[e];
}

// ---------- Phase 3: combine halves, log1p, MLP, sigmoid. One block per b ----
__global__ __launch_bounds__(64)
void knrm_final2(const float* __restrict__ gSqk,
                 const float* __restrict__ W0, const float* __restrict__ b0,
                 const float* __restrict__ W1, const float* __restrict__ b1,
                 const float* __restrict__ W2, const float* __restrict__ b2,
                 float* __restrict__ out, int B)
{
    const int b   = blockIdx.x;
    const int tid = threadIdx.x;

    __shared__ float km[2 * NK];
    __shared__ float h0[2][10];
    __shared__ float h1[2][5];
    __shared__ float lgt[2];

    if (tid < 2 * NK) {
        int pair = tid / NK, k = tid % NK;
        const float* p0 = gSqk + ((((size_t)pair * B + b) * 2 + 0) * (QL * NK));
        const float* p1 = gSqk + ((((size_t)pair * B + b) * 2 + 1) * (QL * NK));
        float s = 0.0f;
        #pragma unroll
        for (int q = 0; q < QL; ++q)
            s += log1pf(p0[q * NK + k] + p1[q * NK + k]);
        km[tid] = s;
    }
    __syncthreads();
    if (tid < 20) {
        int pair = tid / 10, j = tid % 10;
        float h = b0[j];
        #pragma unroll
        for (int k = 0; k < NK; ++k) h = fmaf(km[pair*NK + k], W0[j*NK + k], h);
        h0[pair][j] = fmaxf(h, 0.0f);
    }
    __syncthreads();
    if (tid < 10) {
        int pair = tid / 5, j = tid % 5;
        float h = b1[j];
        #pragma unroll
        for (int i = 0; i < 10; ++i) h = fmaf(h0[pair][i], W1[j*10 + i], h);
        h1[pair][j] = fmaxf(h, 0.0f);
    }
    __syncthreads();
    if (tid < 2) {
        float l = b2[0];
        #pragma unroll
        for (int j = 0; j < 5; ++j) l = fmaf(h1[tid][j], W2[j], l);
        lgt[tid] = l;
    }
    __syncthreads();
    if (tid == 0) {
        float z = lgt[0] - lgt[1];
        out[b] = 1.0f / (1.0f + expf(-z));
    }
}

// ---------- Fallback A (R7 path): table fits but not the Sqk slab ------------
__global__ __launch_bounds__(256, 4)
void knrm_main5(const int* __restrict__ q1t, const int* __restrict__ d1t,
                const int* __restrict__ q2t, const int* __restrict__ d2t,
                const __bf16* __restrict__ tab,
                const float* __restrict__ W0, const float* __restrict__ b0,
                const float* __restrict__ W1, const float* __restrict__ b1,
                const float* __restrict__ W2, const float* __restrict__ b2,
                float* __restrict__ lg, int B)
{
    const int b    = blockIdx.x;
    const int pair = blockIdx.y;
    const int tid  = threadIdx.x;
    const int wave = tid >> 6;
    const int lane = tid & 63;
    const int qt   = wave >> 1;
    const int dt   = wave & 1;
    const int g    = lane >> 4;
    const int cl   = lane & 15;
    const int hl   = lane & 31;
    const int hw   = lane >> 5;

    const int* qtok = pair ? q2t : q1t;
    const int* dtok = pair ? d2t : d1t;

    __shared__ __align__(16) __bf16 qbuf[QL * STR];
    __shared__ __align__(16) __bf16 dbuf[32 * STR];
    __shared__ float Sqk[QL * NK];
    __shared__ int   dtok_s[DL];
    __shared__ int   qtok_s[QL];
    __shared__ float km[NK];
    __shared__ float h0[10];
    __shared__ float h1[5];

    if (tid < QL) qtok_s[tid] = qtok[b * QL + tid];
    dtok_s[tid] = dtok[b * DL + tid];
    for (int e = tid; e < QL * NK; e += 256) Sqk[e] = 0.0f;
    if (tid < NK) km[tid] = 0.0f;
    __syncthreads();

    {
        bf16x8 qv[4];
        #pragma unroll
        for (int i = 0; i < 4; ++i) {
            int r = wave * 8 + i * 2 + hw;
            qv[i] = *reinterpret_cast<const bf16x8*>(
                tab + (size_t)qtok_s[r] * DIM + hl * 8);
        }
        #pragma unroll
        for (int i = 0; i < 4; ++i) {
            int r = wave * 8 + i * 2 + hw;
            *reinterpret_cast<bf16x8*>(&qbuf[r * STR + hl * 8]) = qv[i];
        }
    }

    bf16x8 dreg[4];
    #pragma unroll
    for (int i = 0; i < 4; ++i) {
        int r = wave * 8 + i * 2 + hw;
        dreg[i] = *reinterpret_cast<const bf16x8*>(
            tab + (size_t)dtok_s[r] * DIM + hl * 8);
    }

    const int myq  = qt * 16 + cl;
    const int qtk1 = qtok_s[myq];

    float acc[NK];
    #pragma unroll
    for (int k = 0; k < NK; ++k) acc[k] = 0.0f;

    for (int tile = 0; tile < 8; ++tile) {
        __syncthreads();
        #pragma unroll
        for (int i = 0; i < 4; ++i) {
            int r = wave * 8 + i * 2 + hw;
            *reinterpret_cast<bf16x8*>(&dbuf[r * STR + hl * 8]) = dreg[i];
        }
        if (tile < 7) {
            #pragma unroll
            for (int i = 0; i < 4; ++i) {
                int r = wave * 8 + i * 2 + hw;
                dreg[i] = *reinterpret_cast<const bf16x8*>(
                    tab + (size_t)dtok_s[(tile + 1) * 32 + r] * DIM + hl * 8);
            }
        }
        __syncthreads();

        f32x4 cf = {0.0f, 0.0f, 0.0f, 0.0f};
        #pragma unroll
        for (int ks = 0; ks < 8; ++ks) {
            bf16x8 dfr = *reinterpret_cast<const bf16x8*>(&dbuf[(dt*16 + cl)*STR + ks*32 + g*8]);
            bf16x8 qfr = *reinterpret_cast<const bf16x8*>(&qbuf[(qt*16 + cl)*STR + ks*32 + g*8]);
            cf = __builtin_amdgcn_mfma_f32_16x16x32_bf16(dfr, qfr, cf, 0, 0, 0);
        }

        #pragma unroll
        for (int i = 0; i < 4; ++i) {
            float mm  = cf[i];
            float mm2 = mm * mm;
            #pragma unroll
            for (int k = 0; k < KSOFT; ++k) {
                float mu = -0.95f + 0.1f * (float)k;
                float a1 = 100.0f * L2E * mu;
                float a0 = -50.0f * L2E * mu * mu;
                float arg = fmaf(a1, mm, fmaf(-50.0f * L2E, mm2, a0));
                acc[k] += EXP2F(arg);
            }
            int drow = tile*32 + dt*16 + g*4 + i;
            acc[KSOFT] += (dtok_s[drow] == qtk1) ? 1.0f : 0.0f;
        }
    }

    #pragma unroll
    for (int k = 0; k < NK; ++k)
        atomicAdd(&Sqk[myq * NK + k], acc[k]);
    __syncthreads();

    for (int e = tid; e < QL * NK; e += 256)
        atomicAdd(&km[e % NK], log1pf(Sqk[e]));
    __syncthreads();

    if (tid < 10) {
        float h = b0[tid];
        #pragma unroll
        for (int k = 0; k < NK; ++k) h = fmaf(km[k], W0[tid*NK + k], h);
        h0[tid] = fmaxf(h, 0.0f);
    }
    __syncthreads();
    if (tid < 5) {
        float h = b1[tid];
        #pragma unroll
        for (int j = 0; j < 10; ++j) h = fmaf(h0[j], W1[tid*10 + j], h);
        h1[tid] = fmaxf(h, 0.0f);
    }
    __syncthreads();
    if (tid == 0) {
        float l = b2[0];
        #pragma unroll
        for (int j = 0; j < 5; ++j) l = fmaf(h1[j], W2[j], l);
        lg[pair * B + b] = l;
    }
}

__global__ void knrm_final(const float* __restrict__ lg, float* __restrict__ out, int B)
{
    int i = blockIdx.x * 256 + threadIdx.x;
    if (i < B) {
        float z = lg[i] - lg[B + i];
        out[i] = 1.0f / (1.0f + expf(-z));
    }
}

// ---------- Fallback B (monolithic): ws can't hold the bf16 table ------------
__global__ __launch_bounds__(256, 2)
void knrm_mono(const int* __restrict__ q1t, const int* __restrict__ d1t,
               const int* __restrict__ q2t, const int* __restrict__ d2t,
               const float* __restrict__ emb,
               const float* __restrict__ W0, const float* __restrict__ b0,
               const float* __restrict__ W1, const float* __restrict__ b1,
               const float* __restrict__ W2, const float* __restrict__ b2,
               float* __restrict__ out)
{
    const int b    = blockIdx.x;
    const int tid  = threadIdx.x;
    const int wave = tid >> 6;
    const int lane = tid & 63;
    const int qt   = wave >> 1;
    const int dt   = wave & 1;
    const int g    = lane >> 4;
    const int cl   = lane & 15;

    __shared__ __align__(16) __bf16 qbuf[QL * STR];
    __shared__ __align__(16) __bf16 dbuf[32 * STR];
    __shared__ float Sqk[QL * NK];
    __shared__ int   dtok_s[DL];
    __shared__ int   qtok_s[QL];
    __shared__ float km[NK];
    __shared__ float h0[10];
    __shared__ float h1[5];
    __shared__ float logit[2];

    for (int pair = 0; pair < 2; ++pair) {
        const int* qtok = pair ? q2t : q1t;
        const int* dtok = pair ? d2t : d1t;

        if (tid < QL) qtok_s[tid] = qtok[b * QL + tid];
        dtok_s[tid] = dtok[b * DL + tid];
        for (int e = tid; e < QL * NK; e += 256) Sqk[e] = 0.0f;
        if (tid < NK) km[tid] = 0.0f;
        __syncthreads();

        #pragma unroll
        for (int i = 0; i < 8; ++i) {
            int row = wave * 8 + i;
            int tok = qtok_s[row];
            float4 v = reinterpret_cast<const float4*>(emb + (size_t)tok * DIM)[lane];
            float s = v.x*v.x + v.y*v.y + v.z*v.z + v.w*v.w;
            #pragma unroll
            for (int m = 32; m; m >>= 1) s += __shfl_xor(s, m);
            float inv = rsqrtf(fmaxf(s, 1e-16f));
            bf16x4 o;
            o[0] = (__bf16)(v.x * inv); o[1] = (__bf16)(v.y * inv);
            o[2] = (__bf16)(v.z * inv); o[3] = (__bf16)(v.w * inv);
            *reinterpret_cast<bf16x4*>(&qbuf[row * STR + lane * 4]) = o;
        }

        int qtk[4];
        #pragma unroll
        for (int i = 0; i < 4; ++i) qtk[i] = qtok_s[qt * 16 + g * 4 + i];

        float acc[4 * NK];
        #pragma unroll
        for (int e = 0; e < 4 * NK; ++e) acc[e] = 0.0f;

        for (int tile = 0; tile < 8; ++tile) {
            #pragma unroll
            for (int i = 0; i < 8; ++i) {
                int r = wave * 8 + i;
                int tok = dtok_s[tile * 32 + r];
                float4 v = reinterpret_cast<const float4*>(emb + (size_t)tok * DIM)[lane];
                float s = v.x*v.x + v.y*v.y + v.z*v.z + v.w*v.w;
                #pragma unroll
                for (int m = 32; m; m >>= 1) s += __shfl_xor(s, m);
                float inv = rsqrtf(fmaxf(s, 1e-16f));
                bf16x4 o;
                o[0] = (__bf16)(v.x * inv); o[1] = (__bf16)(v.y * inv);
                o[2] = (__bf16)(v.z * inv); o[3] = (__bf16)(v.w * inv);
                *reinterpret_cast<bf16x4*>(&dbuf[r * STR + lane * 4]) = o;
            }
            __syncthreads();

            f32x4 cf = {0.0f, 0.0f, 0.0f, 0.0f};
            #pragma unroll
            for (int ks = 0; ks < 8; ++ks) {
                bf16x8 af  = *reinterpret_cast<const bf16x8*>(&qbuf[(qt*16 + cl)*STR + ks*32 + g*8]);
                bf16x8 bfr = *reinterpret_cast<const bf16x8*>(&dbuf[(dt*16 + cl)*STR + ks*32 + g*8]);
                cf = __builtin_amdgcn_mfma_f32_16x16x32_bf16(af, bfr, cf, 0, 0, 0);
            }

            int dtk = dtok_s[tile*32 + dt*16 + cl];
            #pragma unroll
            for (int i = 0; i < 4; ++i) {
                float mm  = cf[i];
                float mm2 = mm * mm;
                #pragma unroll
                for (int k = 0; k < KSOFT; ++k) {
                    float mu = -0.95f + 0.1f * (float)k;
                    float a1 = 100.0f * L2E * mu;
                    float a0 = -50.0f * L2E * mu * mu;
                    float arg = fmaf(a1, mm, fmaf(-50.0f * L2E, mm2, a0));
                    acc[i*NK + k] += EXP2F(arg);
                }
                acc[i*NK + KSOFT] += (dtk == qtk[i]) ? 1.0f : 0.0f;
            }
            __syncthreads();
        }

        #pragma unroll
        for (int i = 0; i < 4; ++i) {
            int row = qt*16 + g*4 + i;
            #pragma unroll
            for (int k = 0; k < NK; ++k)
                atomicAdd(&Sqk[row*NK + k], acc[i*NK + k]);
        }
        __syncthreads();

        for (int e = tid; e < QL * NK; e += 256)
            atomicAdd(&km[e % NK], log1pf(Sqk[e]));
        __syncthreads();

        if (tid < 10) {
            float h = b0[tid];
            #pragma unroll
            for (int k = 0; k < NK; ++k) h = fmaf(km[k], W0[tid*NK + k], h);
            h0[tid] = fmaxf(h, 0.0f);
        }
        __syncthreads();
        if (tid < 5) {
            float h = b1[tid];
            #pragma unroll
            for (int j = 0; j < 10; ++j) h = fmaf(h0[j], W1[tid*10 + j], h);
            h1[tid] = fmaxf(h, 0.0f);
        }
        __syncthreads();
        if (tid == 0) {
            float l = b2[0];
            #pragma unroll
            for (int j = 0; j < 5; ++j) l = fmaf(h1[j], W2[j], l);
            logit[pair] = l;
        }
        __syncthreads();
    }

    if (tid == 0) {
        float z = logit[0] - logit[1];
        out[b] = 1.0f / (1.0f + expf(-z));
    }
}

extern "C" void kernel_launch(void* const* d_in, const int* in_sizes, int n_in,
                              void* d_out, int out_size, void* d_ws, size_t ws_size,
                              hipStream_t stream) {
    const int*   q1  = (const int*)d_in[0];
    const int*   d1  = (const int*)d_in[1];
    const int*   q2  = (const int*)d_in[2];
    const int*   d2  = (const int*)d_in[3];
    const float* emb = (const float*)d_in[4];
    const float* W0  = (const float*)d_in[5];
    const float* b0  = (const float*)d_in[6];
    const float* W1  = (const float*)d_in[7];
    const float* b1  = (const float*)d_in[8];
    const float* W2  = (const float*)d_in[9];
    const float* b2  = (const float*)d_in[10];
    float* out = (float*)d_out;

    const int B = in_sizes[0] / QL;       // 512
    const int V = in_sizes[4] / DIM;      // 100000

    size_t tab_bytes  = (size_t)V * DIM * sizeof(__bf16);
    size_t tab_al     = (tab_bytes + 255) & ~(size_t)255;
    size_t sqk_bytes  = (size_t)2 * B * 2 * QL * NK * sizeof(float);   // 5.5 MB
    size_t need_split = tab_al + sqk_bytes;
    size_t need_r7    = tab_al + 256 + (size_t)2 * B * sizeof(float);

    if (ws_size >= need_split) {
        __bf16* tab  = (__bf16*)d_ws;
        float*  gSqk = (float*)((char*)d_ws + tab_al);

        knrm_prep<<<(V + 15) / 16, 256, 0, stream>>>(emb, tab, V);
        dim3 grid(B, 2, 2);
        knrm_main6<<<grid, 256, 0, stream>>>(q1, d1, q2, d2, tab, gSqk, B);
        knrm_final2<<<B, 64, 0, stream>>>(gSqk, W0, b0, W1, b1, W2, b2, out, B);
    } else if (ws_size >= need_r7) {
        __bf16* tab = (__bf16*)d_ws;
        float*  lg  = (float*)((char*)d_ws + tab_al);

        knrm_prep<<<(V + 15) / 16, 256, 0, stream>>>(emb, tab, V);
        dim3 grid(B, 2);
        knrm_main5<<<grid, 256, 0, stream>>>(q1, d1, q2, d2, tab,
                                             W0, b0, W1, b1, W2, b2, lg, B);
        knrm_final<<<(B + 255) / 256, 256, 0, stream>>>(lg, out, B);
    } else {
        knrm_mono<<<B, 256, 0, stream>>>(q1, d1, q2, d2, emb,
                                         W0, b0, W1, b1, W2, b2, out);
    }
}